// Round 8
// baseline (865.300 us; speedup 1.0000x reference)
//
#include <hip/hip_runtime.h>

#define N_NODES  100000
#define N_EDGES  1250000
#define N_GRAPHS 1024
#define NB       ((N_NODES + 127) >> 7)        // 782 buckets of 128 nodes
#define EPB      2048                           // edges per hist/fill block
#define NBLK_F   ((N_EDGES + EPB - 1) / EPB)    // 611 blocks
#define EMB_BLKS ((N_NODES + 255) / 256)        // 391

typedef __attribute__((ext_vector_type(8))) short short8;
typedef __attribute__((ext_vector_type(4))) float f32x4;
union U16 { uint4 u; short8 s; };

// ---- bf16 helpers (round-to-nearest-even) ----
__device__ __forceinline__ float bflo(unsigned int w) { return __uint_as_float(w << 16); }
__device__ __forceinline__ float bfhi(unsigned int w) { return __uint_as_float(w & 0xffff0000u); }
__device__ __forceinline__ unsigned short f2bf(float f) {
  unsigned int u = __float_as_uint(f);
  u = (u + 0x7fffu + ((u >> 16) & 1u)) >> 16;
  return (unsigned short)u;
}

// ------- fused front: embed+lin (blocks 0..390) | bucket histogram (rest) -------
__global__ void __launch_bounds__(256)
k_front(const int* __restrict__ tok,
        const float* __restrict__ semb, const float* __restrict__ cemb,
        const float* __restrict__ lw, const float* __restrict__ lb,
        unsigned short* __restrict__ x1,          // [N,32] bf16
        const int* __restrict__ dst, int* __restrict__ hist) {
  __shared__ int lh[NB];
  const int t = threadIdx.x;
  if (blockIdx.x < EMB_BLKS) {
    int i = blockIdx.x * 256 + t;
    if (i >= N_NODES) return;
    int s = tok[2 * i], c = tok[2 * i + 1];
    float e[16];
#pragma unroll
    for (int k = 0; k < 8; ++k) { e[k] = semb[s * 8 + k]; e[8 + k] = cemb[c * 8 + k]; }
    unsigned int w[16];
#pragma unroll
    for (int o = 0; o < 16; ++o) {
      float a0 = lb[2 * o], a1 = lb[2 * o + 1];
#pragma unroll
      for (int k = 0; k < 16; ++k) {
        a0 = fmaf(e[k], lw[(2 * o) * 16 + k], a0);
        a1 = fmaf(e[k], lw[(2 * o + 1) * 16 + k], a1);
      }
      a0 = fmaxf(a0, 0.f); a1 = fmaxf(a1, 0.f);
      w[o] = (unsigned int)f2bf(a0) | ((unsigned int)f2bf(a1) << 16);
    }
    uint4* d4 = (uint4*)(x1 + (size_t)i * 32);
#pragma unroll
    for (int q = 0; q < 4; ++q)
      d4[q] = make_uint4(w[4 * q], w[4 * q + 1], w[4 * q + 2], w[4 * q + 3]);
  } else {
    const int blk = blockIdx.x - EMB_BLKS;
    for (int i = t; i < NB; i += 256) lh[i] = 0;
    __syncthreads();
    const int start = blk * EPB;
    const int end = min(start + EPB, N_EDGES);
    for (int e = start + t; e < end; e += 256)
      atomicAdd(&lh[dst[e] >> 7], 1);
    __syncthreads();
    for (int i = t; i < NB; i += 256)
      hist[(size_t)i * NBLK_F + blk] = lh[i];
  }
}

// ------- per-bucket exclusive scan across blocks (in place) + bucket totals -------
__global__ void __launch_bounds__(256)
k_colscan(int* __restrict__ hist, int* __restrict__ btotal) {
  __shared__ int part[256];
  const int b = blockIdx.x;
  int* row = hist + (size_t)b * NBLK_F;
  const int t = threadIdx.x;
  constexpr int C = (NBLK_F + 255) / 256;   // 3
  int v[C];
  int s = 0;
#pragma unroll
  for (int j = 0; j < C; ++j) {
    int idx = t * C + j;
    v[j] = (idx < NBLK_F) ? row[idx] : 0;
    s += v[j];
  }
  part[t] = s;
  __syncthreads();
  for (int off = 1; off < 256; off <<= 1) {
    int x = (t >= off) ? part[t - off] : 0;
    __syncthreads();
    part[t] += x;
    __syncthreads();
  }
  int run = part[t] - s;
#pragma unroll
  for (int j = 0; j < C; ++j) {
    int idx = t * C + j;
    if (idx < NBLK_F) { int old = v[j]; row[idx] = run; run += old; }
  }
  if (t == 255) btotal[b] = part[255];
}

// ---------------- bucket-base scan ----------------
__global__ void k_bscan(const int* __restrict__ btotal, int* __restrict__ bbase) {
  __shared__ int s[1024];
  int t = threadIdx.x;
  int d = (t < NB) ? btotal[t] : 0;
  s[t] = d;
  __syncthreads();
  for (int off = 1; off < 1024; off <<= 1) {
    int v = (t >= off) ? s[t - off] : 0;
    __syncthreads();
    s[t] += v;
    __syncthreads();
  }
  if (t < NB) bbase[t] = s[t] - d;
}

// ------- fill: LDS cursors = bbase + scanned per-block offset; scatter -------
__global__ void __launch_bounds__(256)
k_bfill3(const int* __restrict__ src, const int* __restrict__ dst,
         const int* __restrict__ bbase, const int* __restrict__ hist,
         int* __restrict__ tmp) {
  __shared__ int cur[NB];
  const int t = threadIdx.x;
  const int blk = blockIdx.x;
  for (int i = t; i < NB; i += 256)
    cur[i] = bbase[i] + hist[(size_t)i * NBLK_F + blk];
  __syncthreads();
  const int start = blk * EPB;
  const int end = min(start + EPB, N_EDGES);
  for (int e = start + t; e < end; e += 256) {
    int d = dst[e];
    int pos = atomicAdd(&cur[d >> 7], 1);   // LDS cursor only
    tmp[pos] = (src[e] << 7) | (d & 127);
  }
}

// ------- pack Wcat = [wrel; wroot] (2*DIN x 64) into MFMA B-fragments -------
template <int DIN>
__device__ __forceinline__ void prep_body(int t, const float* __restrict__ wrel,
                                          const float* __restrict__ wroot,
                                          unsigned short* __restrict__ Bf) {
  constexpr int NKC = (2 * DIN) / 32;
  if (t >= NKC * 4 * 64) return;
  int l = t & 63;
  int ct = (t >> 6) & 3;
  int kc = t >> 8;
  int col = ct * 16 + (l & 15);
#pragma unroll
  for (int e = 0; e < 8; ++e) {
    int k = kc * 32 + ((l >> 4) << 3) + e;
    float v = (k < DIN) ? wrel[col * DIN + k] : wroot[col * DIN + (k - DIN)];
    Bf[(size_t)t * 8 + e] = f2bf(v);
  }
}

__global__ void k_prep2(const float* __restrict__ w1rel, const float* __restrict__ w1root,
                        const float* __restrict__ w2rel, const float* __restrict__ w2root,
                        unsigned short* __restrict__ Bf1, unsigned short* __restrict__ Bf2) {
  int bid = blockIdx.x;
  if (bid < 2) prep_body<32>(bid * 256 + threadIdx.x, w1rel, w1root, Bf1);
  else prep_body<64>((bid - 2) * 256 + threadIdx.x, w2rel, w2root, Bf2);
}

// ======= fused per-bucket conv: LDS-accumulate edges, then MFMA transform =======
// One block per 128-node bucket. Phase 1: edges from tmp (unsorted) -> ds_add_f32
// into XOR-swizzled accum[128][DIN]. Phase 2: Y = relu([agg|x] @ Wcat + b) via
// mfma_16x16x32_bf16; agg from LDS (f32->bf16), x rows from global (contiguous).
// Swizzle (word idx): row*DIN + ((col>>2 ^ (row&7))<<2) + (col&3).
template <int DIN>
__global__ void __launch_bounds__(256)
k_conv(const int* __restrict__ bbase, const int* __restrict__ btotal,
       const int* __restrict__ tmp,
       const unsigned short* __restrict__ X,    // [N,DIN] bf16
       const uint4* __restrict__ Bf,            // MFMA B-fragments, K=2*DIN
       const float* __restrict__ bias,          // [64]
       unsigned short* __restrict__ Y) {        // [N,64] bf16
  constexpr int NKC = (2 * DIN) / 32;      // 2 (conv1) / 4 (conv2)
  constexpr int LPGu = DIN / 4;            // lanes per edge (uint2 each): 8 / 16
  constexpr int GROUPS = 64 / LPGu;        // 8 / 4
  constexpr int STEP = 16;
  constexpr int UNR = STEP / GROUPS;       // 2 / 4
  __shared__ float accum[128 * DIN];
  const int t = threadIdx.x;
  const int lane = t & 63;
  const int wv = t >> 6;
  const int b = blockIdx.x;
  for (int i = t; i < 128 * DIN; i += 256) accum[i] = 0.f;
  __syncthreads();

  const int ebase = bbase[b];
  const int cnt = btotal[b];
  const int chunk = (cnt + 3) >> 2;
  const int ws = wv * chunk;
  const int we = min(ws + chunk, cnt);
  const int sub = lane / LPGu;
  const int lg = lane % LPGu;
  for (int base = ws; base < we; base += 64) {
    const int lim = min(we - base, 64);
    int myi = 0;
    if (lane < lim) myi = tmp[ebase + base + lane];
    for (int j = 0; j < lim; j += STEP) {
      uint2 r[UNR]; int e[UNR]; int ld[UNR];
#pragma unroll
      for (int u = 0; u < UNR; ++u) {
        e[u] = j + u * GROUPS + sub;                  // always < 64
        int v = __shfl(myi, e[u]);
        ld[u] = v & 127;
        int s = v >> 7;
        r[u] = *((const uint2*)(X + (size_t)s * DIN) + lg);
      }
#pragma unroll
      for (int u = 0; u < UNR; ++u) {
        if (e[u] < lim) {
          float val[4] = { bflo(r[u].x), bfhi(r[u].x), bflo(r[u].y), bfhi(r[u].y) };
          float* rowp = accum + ld[u] * DIN + ((lg ^ (ld[u] & 7)) << 2);
#pragma unroll
          for (int k = 0; k < 4; ++k) {               // rotate by sub: disjoint banks
            int j4 = (k + sub) & 3;
            atomicAdd(rowp + j4, val[j4]);
          }
        }
      }
    }
  }
  __syncthreads();

  // ---- MFMA transform: 8 tiles of 16 nodes; 2 tiles per wave ----
  short8 bf[NKC][4];
#pragma unroll
  for (int kc = 0; kc < NKC; ++kc)
#pragma unroll
    for (int ct = 0; ct < 4; ++ct) { U16 u; u.u = Bf[(kc * 4 + ct) * 64 + lane]; bf[kc][ct] = u.s; }
  float bc[4];
#pragma unroll
  for (int ct = 0; ct < 4; ++ct) bc[ct] = bias[ct * 16 + (lane & 15)];
#pragma unroll
  for (int tt = 0; tt < 2; ++tt) {
    const int tile = wv * 2 + tt;
    const int rl = tile * 16 + (lane & 15);          // local row 0..127
    const int g = (b << 7) + rl;
    const int gs = (g < N_NODES) ? g : 0;            // clamp for loads
    short8 a[NKC];
#pragma unroll
    for (int kc = 0; kc < NKC / 2; ++kc) {           // agg part from LDS
      const int col0 = kc * 32 + ((lane >> 4) << 3);
      const int g0 = col0 >> 2;
      const int rsw = rl & 7;
      f32x4 v0 = *(const f32x4*)(accum + rl * DIN + ((g0 ^ rsw) << 2));
      f32x4 v1 = *(const f32x4*)(accum + rl * DIN + (((g0 + 1) ^ rsw) << 2));
      short8 av;
      av[0] = (short)f2bf(v0.x); av[1] = (short)f2bf(v0.y);
      av[2] = (short)f2bf(v0.z); av[3] = (short)f2bf(v0.w);
      av[4] = (short)f2bf(v1.x); av[5] = (short)f2bf(v1.y);
      av[6] = (short)f2bf(v1.z); av[7] = (short)f2bf(v1.w);
      a[kc] = av;
    }
#pragma unroll
    for (int kc = NKC / 2; kc < NKC; ++kc) {         // root part from global X
      const int colx = (kc - NKC / 2) * 32 + ((lane >> 4) << 3);
      U16 u;
      u.u = *(const uint4*)(X + (size_t)gs * DIN + colx);
      a[kc] = u.s;
    }
#pragma unroll
    for (int ct = 0; ct < 4; ++ct) {
      f32x4 acc = {bc[ct], bc[ct], bc[ct], bc[ct]};
#pragma unroll
      for (int kc = 0; kc < NKC; ++kc)
        acc = __builtin_amdgcn_mfma_f32_16x16x32_bf16(a[kc], bf[kc][ct], acc, 0, 0, 0);
      const int col = ct * 16 + (lane & 15);
#pragma unroll
      for (int j = 0; j < 4; ++j) {
        int grow = (b << 7) + tile * 16 + ((lane >> 4) << 2) + j;
        if (grow < N_NODES)
          Y[(size_t)grow * 64 + col] = f2bf(fmaxf(acc[j], 0.f));
      }
    }
  }
}

// ------- fused mean-pool + classifier: one block per graph, batch is sorted -------
__global__ void __launch_bounds__(256)
k_pool(const unsigned short* __restrict__ y2,   // [N,64] bf16
       const int* __restrict__ batch,
       const float* __restrict__ cw, const float* __restrict__ cb,
       float* __restrict__ out) {
  __shared__ float part[4][64];
  const int g = blockIdx.x;
  const int lane = threadIdx.x & 63;
  const int wv = threadIdx.x >> 6;
  int lo = 0, hi = N_NODES;
  while (lo < hi) { int m = (lo + hi) >> 1; if (batch[m] < g) lo = m + 1; else hi = m; }
  int lo2 = lo, hi2 = N_NODES;
  while (lo2 < hi2) { int m = (lo2 + hi2) >> 1; if (batch[m] < g + 1) lo2 = m + 1; else hi2 = m; }
  float s = 0.f;
  for (int r = lo + wv; r < lo2; r += 4)
    s += __uint_as_float((unsigned int)y2[(size_t)r * 64 + lane] << 16);
  part[wv][lane] = s;
  __syncthreads();
  if (wv == 0) {
    float p = part[0][lane] + part[1][lane] + part[2][lane] + part[3][lane];
    int c_ = lo2 - lo;
    p *= 1.f / (float)(c_ > 0 ? c_ : 1);
    for (int c = 0; c < 10; ++c) {
      float v = p * cw[c * 64 + lane];
#pragma unroll
      for (int off = 1; off < 64; off <<= 1) v += __shfl_xor(v, off);
      if (lane == 0) out[g * 10 + c] = v + cb[c];
    }
  }
}

extern "C" void kernel_launch(void* const* d_in, const int* in_sizes, int n_in,
                              void* d_out, int out_size, void* d_ws, size_t ws_size,
                              hipStream_t stream) {
  const int*   tok    = (const int*)d_in[0];
  const int*   eidx   = (const int*)d_in[1];
  const int*   batch  = (const int*)d_in[2];
  const float* semb   = (const float*)d_in[3];
  const float* cemb   = (const float*)d_in[4];
  const float* lw     = (const float*)d_in[5];
  const float* lb     = (const float*)d_in[6];
  const float* w1rel  = (const float*)d_in[7];
  const float* b1     = (const float*)d_in[8];
  const float* w1root = (const float*)d_in[9];
  const float* w2rel  = (const float*)d_in[10];
  const float* b2     = (const float*)d_in[11];
  const float* w2root = (const float*)d_in[12];
  const float* cw     = (const float*)d_in[13];
  const float* cb     = (const float*)d_in[14];
  const int* src = eidx;
  const int* dst = eidx + N_EDGES;

  char* p = (char*)d_ws;
  unsigned short* X1 = (unsigned short*)p;  p += (size_t)N_NODES * 32 * 2;   // bf16
  unsigned short* X2 = (unsigned short*)p;  p += (size_t)N_NODES * 64 * 2;   // bf16
  unsigned short* Y2 = (unsigned short*)p;  p += (size_t)N_NODES * 64 * 2;   // bf16
  int*   tmp    = (int*)p;    p += (size_t)N_EDGES * 4;
  int*   hist   = (int*)p;    p += (size_t)NB * NBLK_F * 4;   // [bucket][block]
  int*   btotal = (int*)p;    p += 4096;
  int*   bbase  = (int*)p;    p += 4096;
  unsigned short* Bf1 = (unsigned short*)p;  p += 512 * 8 * 2;   // 8KB
  unsigned short* Bf2 = (unsigned short*)p;  p += 1024 * 8 * 2;  // 16KB

  // embed+lin (x1) and per-block bucket histograms, one launch
  k_front<<<EMB_BLKS + NBLK_F, 256, 0, stream>>>(tok, semb, cemb, lw, lb, X1, dst, hist);

  // deterministic counting-sort bucket CSR (no global atomics)
  k_colscan<<<NB, 256, 0, stream>>>(hist, btotal);
  k_bscan<<<1, 1024, 0, stream>>>(btotal, bbase);
  k_bfill3<<<NBLK_F, 256, 0, stream>>>(src, dst, bbase, hist, tmp);

  // weight fragment packing (tiny, independent of scan chain)
  k_prep2<<<6, 256, 0, stream>>>(w1rel, w1root, w2rel, w2root, Bf1, Bf2);

  // fused gather+transform per bucket
  k_conv<32><<<NB, 256, 0, stream>>>(bbase, btotal, tmp, X1, (const uint4*)Bf1, b1, X2);
  k_conv<64><<<NB, 256, 0, stream>>>(bbase, btotal, tmp, X2, (const uint4*)Bf2, b2, Y2);

  // fused mean-pool + classifier
  k_pool<<<N_GRAPHS, 256, 0, stream>>>(Y2, batch, cw, cb, (float*)d_out);
}

// Round 9
// 149.706 us; speedup vs baseline: 5.7800x; 5.7800x over previous
//
#include <hip/hip_runtime.h>

#define N_NODES  100000
#define N_EDGES  1250000
#define N_GRAPHS 1024
#define NB2      (N_NODES / 16)            // 6250 buckets of 16 nodes (exact)
#define CAP      512                        // per-bucket edge capacity (mean 200, ~22 sigma)
#define EMB_BLKS ((N_NODES + 255) / 256)    // 391
#define FILLB    512                        // edge-fill blocks inside k_front

typedef __attribute__((ext_vector_type(8))) short short8;
typedef __attribute__((ext_vector_type(4))) float f32x4;
union U16 { uint4 u; short8 s; };

// ---- bf16 helpers (round-to-nearest-even) ----
__device__ __forceinline__ float bflo(unsigned int w) { return __uint_as_float(w << 16); }
__device__ __forceinline__ float bfhi(unsigned int w) { return __uint_as_float(w & 0xffff0000u); }
__device__ __forceinline__ unsigned short f2bf(float f) {
  unsigned int u = __float_as_uint(f);
  u = (u + 0x7fffu + ((u >> 16) & 1u)) >> 16;
  return (unsigned short)u;
}
__device__ __forceinline__ unsigned int pack2(float a, float b) {
  return (unsigned int)f2bf(a) | ((unsigned int)f2bf(b) << 16);
}

// ------- pack Wcat = [wrel; wroot] (2*DIN x 64) into MFMA B-fragments -------
template <int DIN>
__device__ __forceinline__ void prep_body(int t, const float* __restrict__ wrel,
                                          const float* __restrict__ wroot,
                                          unsigned short* __restrict__ Bf) {
  constexpr int NKC = (2 * DIN) / 32;
  if (t >= NKC * 4 * 64) return;
  int l = t & 63;
  int ct = (t >> 6) & 3;
  int kc = t >> 8;
  int col = ct * 16 + (l & 15);
#pragma unroll
  for (int e = 0; e < 8; ++e) {
    int k = kc * 32 + ((l >> 4) << 3) + e;
    float v = (k < DIN) ? wrel[col * DIN + k] : wroot[col * DIN + (k - DIN)];
    Bf[(size_t)t * 8 + e] = f2bf(v);
  }
}

// ------- fused front: embed+lin | weight prep | bucket edge-fill -------
__global__ void __launch_bounds__(256)
k_front(const int* __restrict__ tok,
        const float* __restrict__ semb, const float* __restrict__ cemb,
        const float* __restrict__ lw, const float* __restrict__ lb,
        unsigned short* __restrict__ x1,          // [N,32] bf16
        const float* __restrict__ w1rel, const float* __restrict__ w1root,
        const float* __restrict__ w2rel, const float* __restrict__ w2root,
        unsigned short* __restrict__ Bf1, unsigned short* __restrict__ Bf2,
        const int* __restrict__ src, const int* __restrict__ dst,
        int* __restrict__ bcur, int* __restrict__ tmp) {
  const int t = threadIdx.x;
  const int bid = blockIdx.x;
  if (bid < EMB_BLKS) {
    // ---- embed + lin ----
    int i = bid * 256 + t;
    if (i >= N_NODES) return;
    int s = tok[2 * i], c = tok[2 * i + 1];
    float e[16];
#pragma unroll
    for (int k = 0; k < 8; ++k) { e[k] = semb[s * 8 + k]; e[8 + k] = cemb[c * 8 + k]; }
    unsigned int w[16];
#pragma unroll
    for (int o = 0; o < 16; ++o) {
      float a0 = lb[2 * o], a1 = lb[2 * o + 1];
#pragma unroll
      for (int k = 0; k < 16; ++k) {
        a0 = fmaf(e[k], lw[(2 * o) * 16 + k], a0);
        a1 = fmaf(e[k], lw[(2 * o + 1) * 16 + k], a1);
      }
      w[o] = pack2(fmaxf(a0, 0.f), fmaxf(a1, 0.f));
    }
    uint4* d4 = (uint4*)(x1 + (size_t)i * 32);
#pragma unroll
    for (int q = 0; q < 4; ++q)
      d4[q] = make_uint4(w[4 * q], w[4 * q + 1], w[4 * q + 2], w[4 * q + 3]);
  } else if (bid < EMB_BLKS + 6) {
    // ---- weight fragment prep ----
    int pb = bid - EMB_BLKS;
    if (pb < 2) prep_body<32>(pb * 256 + t, w1rel, w1root, Bf1);
    else prep_body<64>((pb - 2) * 256 + t, w2rel, w2root, Bf2);
  } else {
    // ---- edge fill: pos = atomic on padded cursor; tmp[b*CAP+pos] = (src<<4)|loc ----
    const int blk = bid - EMB_BLKS - 6;
    const int per = (N_EDGES + FILLB - 1) / FILLB;
    const int start = blk * per;
    const int end = min(start + per, N_EDGES);
    for (int e = start + t; e < end; e += 256) {
      int d = dst[e];
      int b = d >> 4;
      int pos = atomicAdd(&bcur[b * 16], 1);
      if (pos < CAP) tmp[(size_t)b * CAP + pos] = (src[e] << 4) | (d & 15);
    }
  }
}

// ======= fused per-tile conv: LDS count-sort edges, reg-accumulate gather, MFMA =======
// One block per 16-node bucket (= one MFMA row-tile). Wave wv owns local nodes
// wv*4..wv*4+3 (register accumulation), then computes output quadrant ct=wv.
template <int DIN>
__global__ void __launch_bounds__(256)
k_conv(const int* __restrict__ bcur, const int* __restrict__ tmp,
       const unsigned short* __restrict__ X,    // [N,DIN] bf16
       const uint4* __restrict__ Bf,            // MFMA B-fragments, K=2*DIN
       const float* __restrict__ bias,          // [64]
       unsigned short* __restrict__ Y) {        // [N,64] bf16
  constexpr int NKC = (2 * DIN) / 32;      // 2 (conv1) / 4 (conv2)
  constexpr int LPGu = DIN / 4;            // lanes per edge (uint2 slice): 8 / 16
  constexpr int GROUPS = 64 / LPGu;        // 8 / 4
  __shared__ int lsrc[CAP];
  __shared__ int hdeg[16], hbase[16], hcur[16];
  __shared__ unsigned short aggT[(DIN / 8) * 16 * 8];   // [chunk][row][8] bf16
  const int t = threadIdx.x;
  const int lane = t & 63;
  const int wv = t >> 6;
  const int b = blockIdx.x;
  const int cnt = min(bcur[b * 16], CAP);
  if (t < 16) hdeg[t] = 0;
  __syncthreads();
  int w0 = -1, w1 = -1;
  if (t < cnt)       { w0 = tmp[(size_t)b * CAP + t];        atomicAdd(&hdeg[w0 & 15], 1); }
  if (t + 256 < cnt) { w1 = tmp[(size_t)b * CAP + t + 256];  atomicAdd(&hdeg[w1 & 15], 1); }
  __syncthreads();
  if (t == 0) {
    int run = 0;
#pragma unroll
    for (int n = 0; n < 16; ++n) { hbase[n] = run; hcur[n] = run; run += hdeg[n]; }
  }
  __syncthreads();
  if (w0 >= 0) lsrc[atomicAdd(&hcur[w0 & 15], 1)] = w0 >> 4;
  if (w1 >= 0) lsrc[atomicAdd(&hcur[w1 & 15], 1)] = w1 >> 4;
  __syncthreads();

  // ---- gather: wave wv accumulates its 4 nodes in registers ----
  const int sub = lane / LPGu;
  const int lg = lane % LPGu;
#pragma unroll
  for (int k = 0; k < 4; ++k) {
    const int n = wv * 4 + k;
    const int deg = hdeg[n];
    const int base = hbase[n];
    float a0 = 0.f, a1 = 0.f, a2 = 0.f, a3 = 0.f;
    for (int j = 0; j < deg; j += 2 * GROUPS) {
      int e0 = j + sub, e1 = j + GROUPS + sub;
      int s0 = lsrc[base + min(e0, deg - 1)];
      int s1 = lsrc[base + min(e1, deg - 1)];
      uint2 r0 = *((const uint2*)(X + (size_t)s0 * DIN) + lg);
      uint2 r1 = *((const uint2*)(X + (size_t)s1 * DIN) + lg);
      if (e0 < deg) { a0 += bflo(r0.x); a1 += bfhi(r0.x); a2 += bflo(r0.y); a3 += bfhi(r0.y); }
      if (e1 < deg) { a0 += bflo(r1.x); a1 += bfhi(r1.x); a2 += bflo(r1.y); a3 += bfhi(r1.y); }
    }
#pragma unroll
    for (int off = LPGu; off < 64; off <<= 1) {
      a0 += __shfl_xor(a0, off);
      a1 += __shfl_xor(a1, off);
      a2 += __shfl_xor(a2, off);
      a3 += __shfl_xor(a3, off);
    }
    if (sub == 0) {
      uint2 w; w.x = pack2(a0, a1); w.y = pack2(a2, a3);
      *(uint2*)&aggT[(((lg >> 1) * 16 + n) << 3) + ((lg & 1) << 2)] = w;
    }
  }
  __syncthreads();

  // ---- MFMA: this block's 16-row tile, wave wv computes output quadrant ct=wv ----
  short8 bf[NKC];
#pragma unroll
  for (int kc = 0; kc < NKC; ++kc) { U16 u; u.u = Bf[(kc * 4 + wv) * 64 + lane]; bf[kc] = u.s; }
  const float bc = bias[wv * 16 + (lane & 15)];
  const int r = lane & 15;
  const int gg = b * 16 + r;
  short8 a[NKC];
#pragma unroll
  for (int kc = 0; kc < NKC / 2; ++kc) {             // agg part from LDS
    const int chunk = kc * 4 + (lane >> 4);
    U16 u; u.u = *(const uint4*)&aggT[(chunk * 16 + r) << 3];
    a[kc] = u.s;
  }
#pragma unroll
  for (int kc = NKC / 2; kc < NKC; ++kc) {           // root part from global X
    const int colx = (kc - NKC / 2) * 32 + ((lane >> 4) << 3);
    U16 u; u.u = *(const uint4*)(X + (size_t)gg * DIN + colx);
    a[kc] = u.s;
  }
  f32x4 acc = {bc, bc, bc, bc};
#pragma unroll
  for (int kc = 0; kc < NKC; ++kc)
    acc = __builtin_amdgcn_mfma_f32_16x16x32_bf16(a[kc], bf[kc], acc, 0, 0, 0);
  const int col = wv * 16 + (lane & 15);
#pragma unroll
  for (int j = 0; j < 4; ++j) {
    int grow = b * 16 + ((lane >> 4) << 2) + j;
    Y[(size_t)grow * 64 + col] = f2bf(fmaxf(acc[j], 0.f));
  }
}

// ------- fused mean-pool + classifier: one block per graph, batch is sorted -------
__global__ void __launch_bounds__(256)
k_pool(const unsigned short* __restrict__ y2,   // [N,64] bf16
       const int* __restrict__ batch,
       const float* __restrict__ cw, const float* __restrict__ cb,
       float* __restrict__ out) {
  __shared__ float part[4][64];
  const int g = blockIdx.x;
  const int lane = threadIdx.x & 63;
  const int wv = threadIdx.x >> 6;
  int lo = 0, hi = N_NODES;
  while (lo < hi) { int m = (lo + hi) >> 1; if (batch[m] < g) lo = m + 1; else hi = m; }
  int lo2 = lo, hi2 = N_NODES;
  while (lo2 < hi2) { int m = (lo2 + hi2) >> 1; if (batch[m] < g + 1) lo2 = m + 1; else hi2 = m; }
  float s = 0.f;
  for (int r = lo + wv; r < lo2; r += 4)
    s += __uint_as_float((unsigned int)y2[(size_t)r * 64 + lane] << 16);
  part[wv][lane] = s;
  __syncthreads();
  if (wv == 0) {
    float p = part[0][lane] + part[1][lane] + part[2][lane] + part[3][lane];
    int c_ = lo2 - lo;
    p *= 1.f / (float)(c_ > 0 ? c_ : 1);
    for (int c = 0; c < 10; ++c) {
      float v = p * cw[c * 64 + lane];
#pragma unroll
      for (int off = 1; off < 64; off <<= 1) v += __shfl_xor(v, off);
      if (lane == 0) out[g * 10 + c] = v + cb[c];
    }
  }
}

extern "C" void kernel_launch(void* const* d_in, const int* in_sizes, int n_in,
                              void* d_out, int out_size, void* d_ws, size_t ws_size,
                              hipStream_t stream) {
  const int*   tok    = (const int*)d_in[0];
  const int*   eidx   = (const int*)d_in[1];
  const int*   batch  = (const int*)d_in[2];
  const float* semb   = (const float*)d_in[3];
  const float* cemb   = (const float*)d_in[4];
  const float* lw     = (const float*)d_in[5];
  const float* lb     = (const float*)d_in[6];
  const float* w1rel  = (const float*)d_in[7];
  const float* b1     = (const float*)d_in[8];
  const float* w1root = (const float*)d_in[9];
  const float* w2rel  = (const float*)d_in[10];
  const float* b2     = (const float*)d_in[11];
  const float* w2root = (const float*)d_in[12];
  const float* cw     = (const float*)d_in[13];
  const float* cb     = (const float*)d_in[14];
  const int* src = eidx;
  const int* dst = eidx + N_EDGES;

  char* p = (char*)d_ws;
  unsigned short* X1 = (unsigned short*)p;  p += (size_t)N_NODES * 32 * 2;   // 6.4 MB
  unsigned short* X2 = (unsigned short*)p;  p += (size_t)N_NODES * 64 * 2;   // 12.8 MB
  unsigned short* Y2 = (unsigned short*)p;  p += (size_t)N_NODES * 64 * 2;   // 12.8 MB
  int*   tmp  = (int*)p;  p += (size_t)NB2 * CAP * 4;                        // 12.8 MB
  int*   bcur = (int*)p;  p += (size_t)NB2 * 64;                             // 0.4 MB padded
  unsigned short* Bf1 = (unsigned short*)p;  p += 512 * 8 * 2;   // 8 KB
  unsigned short* Bf2 = (unsigned short*)p;  p += 1024 * 8 * 2;  // 16 KB

  hipMemsetAsync(bcur, 0, (size_t)NB2 * 64, stream);

  // embed+lin | weight prep | edge fill — one launch, independent block ranges
  k_front<<<EMB_BLKS + 6 + FILLB, 256, 0, stream>>>(
      tok, semb, cemb, lw, lb, X1,
      w1rel, w1root, w2rel, w2root, Bf1, Bf2,
      src, dst, bcur, tmp);

  // fused per-tile conv layers
  k_conv<32><<<NB2, 256, 0, stream>>>(bcur, tmp, X1, (const uint4*)Bf1, b1, X2);
  k_conv<64><<<NB2, 256, 0, stream>>>(bcur, tmp, X2, (const uint4*)Bf2, b2, Y2);

  // fused mean-pool + classifier
  k_pool<<<N_GRAPHS, 256, 0, stream>>>(Y2, batch, cw, cb, (float*)d_out);
}